// Round 4
// baseline (17300.014 us; speedup 1.0000x reference)
//
#include <hip/hip_runtime.h>
#include <cstdint>
#include <cstddef>

typedef float f32x4 __attribute__((ext_vector_type(4)));
typedef unsigned int u32x4 __attribute__((ext_vector_type(4)));

#define H     1024
#define BATCH 16
#define SEQ   2000
#define NOUT  8
#define G     64       // persistent workgroups, 16 rows each
#define RPW   16
#define TPB   256

// d_out offsets (floats): n_all, h_all, r_all, u_all, z_all
#define N_OFF 0
#define H_OFF 32768000
#define R_OFF 65536000
#define U_OFF 98304000
#define Z_OFF 131072000

// ws layout (bytes)
#define FLAGS_OFF 0          // 256 packed u32 wave-flags (1KB)
#define SBUF_OFF  8192       // double-buffered s: 2 * 16*1024 floats, layout [b][row]
#define IREP_OFF  139264     // I repacked [t][b] (+64B pad for prefetch overrun)
#define ZPART_OFF 267328     // zpart [t][g][b]

__global__ void init_kernel(const float* __restrict__ I, float* __restrict__ Irep,
                            unsigned int* __restrict__ flags) {
  int tid = blockIdx.x * blockDim.x + threadIdx.x;
  if (tid < SEQ * BATCH) {
    int t = tid >> 4, b = tid & 15;
    Irep[tid] = I[b * SEQ + t];            // I is [B, SEQ, 1]
  }
  if (tid < 4 * G) flags[tid] = 0u;
}

__global__ __launch_bounds__(TPB, 1) void rnn_persist(
    const float* __restrict__ h0, const float* __restrict__ r0, const float* __restrict__ u0,
    const float* __restrict__ Wih, const float* __restrict__ offih,
    const float* __restrict__ Whh, const float* __restrict__ Whz,
    const float* __restrict__ prel, const float* __restrict__ Whhm, const float* __restrict__ Whzm,
    const float* __restrict__ Irep, float* __restrict__ sbuf, unsigned int* __restrict__ flags,
    float* __restrict__ zpart, float* __restrict__ dout)
{
  __shared__ float wL[RPW][H];   // 64KB masked W_hh rows, resident all 2000 steps

  const int g = blockIdx.x, tid = threadIdx.x;
  const int lane = tid & 63, w = tid >> 6;
  const int ro = lane >> 2;              // row within WG   (butterfly output = lane)
  const int bo = (w << 2) + (lane & 3);  // batch owned by this lane
  const int row = g * RPW + ro;

  // ---- one-time: masked W_hh rows -> LDS ----
  {
    const f32x4* wsrc = (const f32x4*)(Whh + (size_t)g * RPW * H);
    const f32x4* msrc = (const f32x4*)(Whhm + (size_t)g * RPW * H);
    for (int k = tid; k < RPW * H / 4; k += TPB)
      ((f32x4*)&wL[0][0])[k] = wsrc[k] * msrc[k];
  }
  __syncthreads();   // only barrier in the whole kernel

  // ---- per-lane persistent state ----
  const int sidx = bo * H + row;         // sbuf layout [b][row]
  float h  = h0[sidx], rr_ = r0[sidx], u = u0[sidx];
  float p  = prel[row], psyn = 1.0f / p;
  float wih = Wih[row], oih = offih[row];
  const int o = row >> 7;
  float wz = Whz[o * H + row] * Whzm[o * H + row];
  float ht = 1.0f / (1.0f + __expf(-8.0f * (h - 0.5f)));

  const float INV_TAU = 1.0f / 0.01f, INV_TD = 1.0f / 0.2f, INV_TF = 1.0f / 1.5f;

  unsigned int* myflag = flags + (g << 2) + w;
  const unsigned int* pollp = flags + (lane << 2);   // lane reads 4 packed flags

  // ---- publish s_0 (write-through to MALL), ack, set wave flag ----
  {
    float s0 = ht * rr_ * u * psyn;
    float* ap = sbuf + sidx;
    asm volatile("global_store_dword %0, %1, off sc0 sc1" :: "v"(ap), "v"(s0) : "memory");
    asm volatile("s_waitcnt vmcnt(0)" ::: "memory");
    if (lane == 0)
      asm volatile("global_store_dword %0, %1, off sc0 sc1" :: "v"(myflag), "v"(1u) : "memory");
  }

  float* ph = dout + H_OFF + (size_t)bo * (SEQ * H) + row;
  float* pr = dout + R_OFF + (size_t)bo * (SEQ * H) + row;
  float* pu = dout + U_OFF + (size_t)bo * (SEQ * H) + row;
  float* pz = zpart + (size_t)g * BATCH + (w << 2) + lane;  // valid when lane < 4
  const float* ip = Irep + bo;
  float Itc = ip[0];                      // prefetched I_t

#define ISSUE(c) { _Pragma("unroll") for (int m = 0; m < 4; ++m) { \
    const float* ap = sb + ((w << 2) + m) * H + (c) * 256 + (lane << 2); \
    asm volatile("global_load_dwordx4 %0, %1, off" : "=v"(ld[c][m]) : "v"(ap)); } }

#define DO_CHUNK(c) { const int c4 = (c) * 64 + lane; \
  _Pragma("unroll") for (int i = 0; i < 16; ++i) { \
    f32x4 wv = ((const f32x4*)&wL[i][0])[c4]; \
    _Pragma("unroll") for (int m = 0; m < 4; ++m) { \
      float a = acc[i * 4 + m]; f32x4 sv = ld[c][m]; \
      a = fmaf(wv.x, sv.x, a); a = fmaf(wv.y, sv.y, a); \
      a = fmaf(wv.z, sv.z, a); a = fmaf(wv.w, sv.w, a); \
      acc[i * 4 + m] = a; } } }

#define WAITV(n) { asm volatile("s_waitcnt vmcnt(" #n ")" ::: "memory"); \
                   __builtin_amdgcn_sched_barrier(0); }

  for (int t = 0; t < SEQ; ++t) {
    // ---- wait until all 256 waves have published s_t ----
    const unsigned int tgt = (unsigned int)(t + 1);
    for (int it = 0; it < (1 << 16); ++it) {
      u32x4 f;
      asm volatile("global_load_dwordx4 %0, %1, off sc0 sc1" : "=v"(f) : "v"(pollp) : "memory");
      asm volatile("s_waitcnt vmcnt(0)" ::: "memory");
      int ok = (f.x >= tgt) & (f.y >= tgt) & (f.z >= tgt) & (f.w >= tgt);
      if (__all(ok)) break;
    }
    // acquire: drop stale L1/L2 lines so cached loads see MALL-fresh s_t
    __builtin_amdgcn_fence(__ATOMIC_ACQUIRE, "agent");
    __builtin_amdgcn_sched_barrier(0);

    // ---- fetch s_t for this wave's 4 batches (cached; L2 shared per XCD) ----
    const float* sb = sbuf + (t & 1) * (BATCH * H);
    f32x4 ld[4][4];
    float acc[64];
    #pragma unroll
    for (int q = 0; q < 64; ++q) acc[q] = 0.0f;

    ISSUE(0); ISSUE(1);
    WAITV(4);  DO_CHUNK(0);  ISSUE(2);
    WAITV(4);  DO_CHUNK(1);  ISSUE(3);
    WAITV(4);  DO_CHUNK(2);
    WAITV(0);  DO_CHUNK(3);

    // ---- butterfly: sum 64 j-slices; lane l ends with output (ro=l>>2, m=l&3) ----
    #pragma unroll
    for (int k = 0; k < 6; ++k) {
      const int d = 1 << k;
      const bool bit = (lane >> k) & 1;
      #pragma unroll
      for (int m = 0; m < (32 >> k); ++m) {
        float a = acc[2 * m], b2 = acc[2 * m + 1];
        float send = bit ? a : b2;
        float keep = bit ? b2 : a;
        acc[m] = keep + __shfl_xor(send, d);
      }
    }
    float rec = acc[0];

    // ---- state update (n == 0 identically) ----
    float ext = Itc * wih + oih;
    float hn  = h + ((-h + rec + ext) * INV_TAU) * 0.001f;
    float htn = 1.0f / (1.0f + __expf(-8.0f * (hn - 0.5f)));
    float rn  = rr_ + ((1.0f - rr_) * INV_TD - 50.0f * u * rr_ * ht) * 0.001f;
    float un  = u + ((p - u) * INV_TF + 50.0f * p * (1.0f - u) * ht) * 0.001f;

    // ---- publish s_{t+1} first (critical path): store, ack, wave flag ----
    float sn = htn * rn * un * psyn;
    {
      float* ap = sbuf + ((t + 1) & 1) * (BATCH * H) + sidx;
      asm volatile("global_store_dword %0, %1, off sc0 sc1" :: "v"(ap), "v"(sn) : "memory");
      asm volatile("s_waitcnt vmcnt(0)" ::: "memory");
      if (lane == 0)
        asm volatile("global_store_dword %0, %1, off sc0 sc1"
                     :: "v"(myflag), "v"((unsigned int)(t + 2)) : "memory");
    }

    // ---- outputs (overlap other WGs' polling) ----
    ph[(size_t)t * H] = hn; pr[(size_t)t * H] = rn; pu[(size_t)t * H] = un;
    float zl = htn * wz;
    zl += __shfl_xor(zl, 4); zl += __shfl_xor(zl, 8);
    zl += __shfl_xor(zl, 16); zl += __shfl_xor(zl, 32);
    if (lane < 4) pz[(size_t)t * (G * BATCH)] = zl;

    Itc = ip[(size_t)(t + 1) * BATCH];   // prefetch next I (64B pad covers t+1==SEQ)
    h = hn; ht = htn; rr_ = rn; u = un;
  }
#undef ISSUE
#undef DO_CHUNK
#undef WAITV
}

__global__ void zred_kernel(const float* __restrict__ zpart, const float* __restrict__ offhz,
                            float* __restrict__ zout) {
  int tid = blockIdx.x * blockDim.x + threadIdx.x;
  if (tid >= BATCH * SEQ * NOUT) return;
  int b = tid / (SEQ * NOUT);
  int rem = tid - b * (SEQ * NOUT);
  int t = rem >> 3, o = rem & 7;
  float acc = offhz[o];
  #pragma unroll
  for (int k = 0; k < G / NOUT; ++k)
    acc += zpart[((size_t)t * G + o * (G / NOUT) + k) * BATCH + b];
  zout[tid] = acc;
}

extern "C" void kernel_launch(void* const* d_in, const int* in_sizes, int n_in,
                              void* d_out, int out_size, void* d_ws, size_t ws_size,
                              hipStream_t stream) {
  const float* I     = (const float*)d_in[0];
  const float* h0    = (const float*)d_in[1];
  const float* r0    = (const float*)d_in[2];
  const float* u0    = (const float*)d_in[3];
  const float* Wih   = (const float*)d_in[4];
  const float* offih = (const float*)d_in[5];
  const float* Whh   = (const float*)d_in[6];
  const float* Whz   = (const float*)d_in[7];
  const float* offhz = (const float*)d_in[8];
  const float* prel  = (const float*)d_in[9];
  const float* Whhm  = (const float*)d_in[10];
  const float* Whzm  = (const float*)d_in[11];
  float* out = (float*)d_out;

  unsigned int* flags = (unsigned int*)((char*)d_ws + FLAGS_OFF);
  float* sbuf  = (float*)((char*)d_ws + SBUF_OFF);
  float* Irep  = (float*)((char*)d_ws + IREP_OFF);
  float* zpart = (float*)((char*)d_ws + ZPART_OFF);

  hipMemsetAsync(d_out, 0, (size_t)H_OFF * sizeof(float), stream);  // n_all == 0
  init_kernel<<<(SEQ * BATCH + 255) / 256, 256, 0, stream>>>(I, Irep, flags);
  rnn_persist<<<G, TPB, 0, stream>>>(h0, r0, u0, Wih, offih, Whh, Whz, prel, Whhm, Whzm,
                                     Irep, sbuf, flags, zpart, out);
  zred_kernel<<<(BATCH * SEQ * NOUT + 255) / 256, 256, 0, stream>>>(zpart, offhz, out + Z_OFF);
}

// Round 5
// 12981.219 us; speedup vs baseline: 1.3327x; 1.3327x over previous
//
#include <hip/hip_runtime.h>
#include <cstdint>
#include <cstddef>

typedef float f32x4 __attribute__((ext_vector_type(4)));
typedef unsigned int u32x4 __attribute__((ext_vector_type(4)));
typedef unsigned int u32x2 __attribute__((ext_vector_type(2)));

#define H     1024
#define BATCH 16
#define SEQ   2000
#define NOUT  8
#define G     64       // persistent workgroups, 16 rows each
#define RPW   16
#define TPB   256

// d_out offsets (floats): n_all, h_all, r_all, u_all, z_all
#define N_OFF 0
#define H_OFF 32768000
#define R_OFF 65536000
#define U_OFF 98304000
#define Z_OFF 131072000

// ws layout (bytes)
#define SBUF2_OFF 8192                       // (val,tag) pairs: 2 * 16384 * 8B = 256KB
#define IREP_OFF  (8192 + 262144)            // I repacked [t][b] (+64B pad)
#define ZPART_OFF (IREP_OFF + 128256 + 128)  // zpart [t][g][b]

__global__ void init_kernel(const float* __restrict__ I, float* __restrict__ Irep,
                            unsigned int* __restrict__ sbuf2) {
  int tid = blockIdx.x * blockDim.x + threadIdx.x;
  if (tid < SEQ * BATCH) {
    int t = tid >> 4, b = tid & 15;
    Irep[tid] = I[b * SEQ + t];            // I is [B, SEQ, 1]
  }
  if (tid < 2 * BATCH * H) {               // zero ALL tags (both parities)
    unsigned int* ap = sbuf2 + tid * 2 + 1;
    unsigned int z = 0;
    asm volatile("global_store_dword %0, %1, off sc0 sc1" :: "v"(ap), "v"(z) : "memory");
  }
}

__global__ __launch_bounds__(TPB, 1) void rnn_persist(
    const float* __restrict__ h0, const float* __restrict__ r0, const float* __restrict__ u0,
    const float* __restrict__ Wih, const float* __restrict__ offih,
    const float* __restrict__ Whh, const float* __restrict__ Whz,
    const float* __restrict__ prel, const float* __restrict__ Whhm, const float* __restrict__ Whzm,
    const float* __restrict__ Irep, unsigned int* __restrict__ sbuf2,
    float* __restrict__ zpart, float* __restrict__ dout)
{
  __shared__ float wL[RPW][H];   // 64KB masked W_hh rows, resident all 2000 steps

  const int g = blockIdx.x, tid = threadIdx.x;
  const int lane = tid & 63, w = tid >> 6;
  const int ro = lane >> 2;              // row within WG   (butterfly output = lane)
  const int bo = (w << 2) + (lane & 3);  // batch owned by this lane
  const int row = g * RPW + ro;

  // ---- one-time: masked W_hh rows -> LDS ----
  {
    const f32x4* wsrc = (const f32x4*)(Whh + (size_t)g * RPW * H);
    const f32x4* msrc = (const f32x4*)(Whhm + (size_t)g * RPW * H);
    for (int k = tid; k < RPW * H / 4; k += TPB)
      ((f32x4*)&wL[0][0])[k] = wsrc[k] * msrc[k];
  }
  __syncthreads();   // only barrier in the whole kernel

  // ---- per-lane persistent state ----
  const int sidx = bo * H + row;         // element index, layout [b][row]
  float h  = h0[sidx], rr_ = r0[sidx], u = u0[sidx];
  float p  = prel[row], psyn = 1.0f / p;
  float wih = Wih[row], oih = offih[row];
  const int o = row >> 7;
  float wz = Whz[o * H + row] * Whzm[o * H + row];
  float ht = 1.0f / (1.0f + __expf(-8.0f * (h - 0.5f)));

  const float INV_TAU = 1.0f / 0.01f, INV_TD = 1.0f / 0.2f, INV_TF = 1.0f / 1.5f;

  // ---- publish s_0 as (val, tag=1): fire-and-forget write-through ----
  {
    u32x2 pv; pv.x = __float_as_uint(ht * rr_ * u * psyn); pv.y = 1u;
    unsigned int* ap = sbuf2 + (size_t)sidx * 2;
    asm volatile("global_store_dwordx2 %0, %1, off sc0 sc1" :: "v"(ap), "v"(pv) : "memory");
  }

  float* ph = dout + H_OFF + (size_t)bo * (SEQ * H) + row;
  float* pr = dout + R_OFF + (size_t)bo * (SEQ * H) + row;
  float* pu = dout + U_OFF + (size_t)bo * (SEQ * H) + row;
  float* pz = zpart + (size_t)g * BATCH + (w << 2) + lane;  // valid when lane < 4
  const float* ip = Irep + bo;
  float Itc = ip[0];                      // prefetched I_t

// chunk c covers j in [c*256, c*256+256); lane holds j = c*256 + 4*lane + {0..3}
// (val,tag) pair for element e at u32 index 2e; dwordx4 = elements e, e+1
#define ISSUE(buf, c) { _Pragma("unroll") for (int m = 0; m < 4; ++m) \
  _Pragma("unroll") for (int q = 0; q < 2; ++q) { \
    const unsigned int* ap = sb2 + ((((size_t)((w << 2) + m) * H) + (c) * 256 + (lane << 2) + (q << 1)) << 1); \
    asm volatile("global_load_dwordx4 %0, %1, off sc0 sc1" \
                 : "=v"(ld[buf][m * 2 + q]) : "v"(ap) : "memory"); } }

#define CHECK(buf, okv) { int okl = 1; \
  _Pragma("unroll") for (int k2 = 0; k2 < 8; ++k2) \
    okl &= (int)(ld[buf][k2].y == tgt) & (int)(ld[buf][k2].w == tgt); \
  okv = __all(okl); }

#define DO_CHUNK(buf, c) { const int c4 = (c) * 64 + lane; \
  _Pragma("unroll") for (int i = 0; i < 16; ++i) { \
    f32x4 wv = ((const f32x4*)&wL[i][0])[c4]; \
    _Pragma("unroll") for (int m = 0; m < 4; ++m) { \
      float a = acc[i * 4 + m]; \
      a = fmaf(wv.x, __uint_as_float(ld[buf][m * 2 + 0].x), a); \
      a = fmaf(wv.y, __uint_as_float(ld[buf][m * 2 + 0].z), a); \
      a = fmaf(wv.z, __uint_as_float(ld[buf][m * 2 + 1].x), a); \
      a = fmaf(wv.w, __uint_as_float(ld[buf][m * 2 + 1].z), a); \
      acc[i * 4 + m] = a; } } }

#define WAITV(n) { asm volatile("s_waitcnt vmcnt(" #n ")" ::: "memory"); \
                   __builtin_amdgcn_sched_barrier(0); }

#define VERIFY(buf, c) { int ok; CHECK(buf, ok); int guard = 0; \
  while (!ok && ++guard < (1 << 14)) { ISSUE(buf, c); WAITV(0); CHECK(buf, ok); } }

  for (int t = 0; t < SEQ; ++t) {
    const unsigned int tgt = (unsigned int)(t + 1);
    const unsigned int* sb2 = sbuf2 + (size_t)(t & 1) * (BATCH * H * 2);
    u32x4 ld[2][8];
    float acc[64];
    #pragma unroll
    for (int q = 0; q < 64; ++q) acc[q] = 0.0f;

    ISSUE(0, 0); ISSUE(1, 1);
    WAITV(8);  VERIFY(0, 0);  DO_CHUNK(0, 0);  ISSUE(0, 2);
    WAITV(8);  VERIFY(1, 1);  DO_CHUNK(1, 1);  ISSUE(1, 3);
    WAITV(8);  VERIFY(0, 2);  DO_CHUNK(0, 2);
    WAITV(0);  VERIFY(1, 3);  DO_CHUNK(1, 3);

    // ---- butterfly: sum 64 j-slices; lane l ends with output (ro=l>>2, m=l&3) ----
    #pragma unroll
    for (int k = 0; k < 6; ++k) {
      const int d = 1 << k;
      const bool bit = (lane >> k) & 1;
      #pragma unroll
      for (int m = 0; m < (32 >> k); ++m) {
        float a = acc[2 * m], b2 = acc[2 * m + 1];
        float send = bit ? a : b2;
        float keep = bit ? b2 : a;
        acc[m] = keep + __shfl_xor(send, d);
      }
    }
    float rec = acc[0];

    // ---- state update (n == 0 identically) ----
    float ext = Itc * wih + oih;
    float hn  = h + ((-h + rec + ext) * INV_TAU) * 0.001f;
    float htn = 1.0f / (1.0f + __expf(-8.0f * (hn - 0.5f)));
    float rn  = rr_ + ((1.0f - rr_) * INV_TD - 50.0f * u * rr_ * ht) * 0.001f;
    float un  = u + ((p - u) * INV_TF + 50.0f * p * (1.0f - u) * ht) * 0.001f;

    // ---- publish s_{t+1}: single 8B (val,tag) store, no ack ----
    float sn = htn * rn * un * psyn;
    {
      u32x2 pv; pv.x = __float_as_uint(sn); pv.y = (unsigned int)(t + 2);
      unsigned int* ap = sbuf2 + (size_t)((t + 1) & 1) * (BATCH * H * 2) + (size_t)sidx * 2;
      asm volatile("global_store_dwordx2 %0, %1, off sc0 sc1" :: "v"(ap), "v"(pv) : "memory");
    }

    // ---- outputs (overlap other WGs' detect) ----
    ph[(size_t)t * H] = hn; pr[(size_t)t * H] = rn; pu[(size_t)t * H] = un;
    float zl = htn * wz;
    zl += __shfl_xor(zl, 4); zl += __shfl_xor(zl, 8);
    zl += __shfl_xor(zl, 16); zl += __shfl_xor(zl, 32);
    if (lane < 4) pz[(size_t)t * (G * BATCH)] = zl;

    Itc = ip[(size_t)(t + 1) * BATCH];   // prefetch next I (pad covers t+1==SEQ)
    h = hn; ht = htn; rr_ = rn; u = un;
  }
#undef ISSUE
#undef CHECK
#undef DO_CHUNK
#undef WAITV
#undef VERIFY
}

__global__ void zred_kernel(const float* __restrict__ zpart, const float* __restrict__ offhz,
                            float* __restrict__ zout) {
  int tid = blockIdx.x * blockDim.x + threadIdx.x;
  if (tid >= BATCH * SEQ * NOUT) return;
  int b = tid / (SEQ * NOUT);
  int rem = tid - b * (SEQ * NOUT);
  int t = rem >> 3, o = rem & 7;
  float acc = offhz[o];
  #pragma unroll
  for (int k = 0; k < G / NOUT; ++k)
    acc += zpart[((size_t)t * G + o * (G / NOUT) + k) * BATCH + b];
  zout[tid] = acc;
}

extern "C" void kernel_launch(void* const* d_in, const int* in_sizes, int n_in,
                              void* d_out, int out_size, void* d_ws, size_t ws_size,
                              hipStream_t stream) {
  const float* I     = (const float*)d_in[0];
  const float* h0    = (const float*)d_in[1];
  const float* r0    = (const float*)d_in[2];
  const float* u0    = (const float*)d_in[3];
  const float* Wih   = (const float*)d_in[4];
  const float* offih = (const float*)d_in[5];
  const float* Whh   = (const float*)d_in[6];
  const float* Whz   = (const float*)d_in[7];
  const float* offhz = (const float*)d_in[8];
  const float* prel  = (const float*)d_in[9];
  const float* Whhm  = (const float*)d_in[10];
  const float* Whzm  = (const float*)d_in[11];
  float* out = (float*)d_out;

  unsigned int* sbuf2 = (unsigned int*)((char*)d_ws + SBUF2_OFF);
  float* Irep  = (float*)((char*)d_ws + IREP_OFF);
  float* zpart = (float*)((char*)d_ws + ZPART_OFF);

  hipMemsetAsync(d_out, 0, (size_t)H_OFF * sizeof(float), stream);  // n_all == 0
  init_kernel<<<128, 256, 0, stream>>>(I, Irep, sbuf2);
  rnn_persist<<<G, TPB, 0, stream>>>(h0, r0, u0, Wih, offih, Whh, Whz, prel, Whhm, Whzm,
                                     Irep, sbuf2, zpart, out);
  zred_kernel<<<(BATCH * SEQ * NOUT + 255) / 256, 256, 0, stream>>>(zpart, offhz, out + Z_OFF);
}

// Round 6
// 6957.715 us; speedup vs baseline: 2.4865x; 1.8657x over previous
//
#include <hip/hip_runtime.h>
#include <cstdint>
#include <cstddef>

typedef float f32x4 __attribute__((ext_vector_type(4)));
typedef unsigned int u32x4 __attribute__((ext_vector_type(4)));
typedef short s16x8 __attribute__((ext_vector_type(8)));

#define H     1024
#define BATCH 16
#define SEQ   2000
#define NOUT  8
#define G     64       // persistent workgroups, 16 rows each
#define RPW   16
#define TPB   256

// d_out offsets (floats): n_all, h_all, r_all, u_all, z_all
#define H_OFF 32768000
#define R_OFF 65536000
#define U_OFF 98304000
#define Z_OFF 131072000

// ws layout (bytes)
#define FLAGS_OFF 0          // 256 per-wave u32 flags (1KB)
#define SBUF_OFF  8192       // double-buffered packed s: 2 * 16384 u32 = 128KB, layout [j>>3][b][j&7]
#define IREP_OFF  139264     // I repacked [t][b] (+pad)
#define ZPART_OFF 267392     // zpart [t][g][b]

__global__ void init_kernel(const float* __restrict__ I, float* __restrict__ Irep,
                            unsigned int* __restrict__ flags) {
  int tid = blockIdx.x * blockDim.x + threadIdx.x;
  if (tid < SEQ * BATCH) {
    int t = tid >> 4, b = tid & 15;
    Irep[tid] = I[b * SEQ + t];            // I is [B, SEQ, 1]
  }
  if (tid < 4 * G) {
    unsigned int* ap = flags + tid; unsigned int z = 0;
    asm volatile("global_store_dword %0, %1, off sc0 sc1" :: "v"(ap), "v"(z) : "memory");
  }
}

// split f into truncated-bf16 hi + truncated-bf16 lo, packed (hi<<16)|lo
__device__ __forceinline__ unsigned int pack_split(float f) {
  unsigned int uh = __float_as_uint(f) & 0xffff0000u;
  float fl = f - __uint_as_float(uh);
  return uh | (__float_as_uint(fl) >> 16);
}

__global__ __launch_bounds__(TPB, 1) void rnn_persist(
    const float* __restrict__ h0, const float* __restrict__ r0, const float* __restrict__ u0,
    const float* __restrict__ Wih, const float* __restrict__ offih,
    const float* __restrict__ Whh, const float* __restrict__ Whz,
    const float* __restrict__ prel, const float* __restrict__ Whhm, const float* __restrict__ Whzm,
    const float* __restrict__ Irep, unsigned int* __restrict__ sbuf,
    unsigned int* __restrict__ flags, float* __restrict__ zpart, float* __restrict__ dout)
{
  __shared__ float redC[2][4][16][16];   // [parity][wave][row][batch] K-partials

  const int g = blockIdx.x, tid = threadIdx.x;
  const int lane = tid & 63, w = tid >> 6;
  const int arow  = lane & 15;           // MFMA A row / C col
  const int klane = lane >> 4;           // 0..3: k-subgroup
  const int ro = lane >> 2, bo = (w << 2) + (lane & 3);   // owned state (row, batch)
  const int row = g * RPW + ro;

  // ---- one-time: masked W_hh -> split-bf16 fragments in VGPRs (64 regs) ----
  s16x8 ahi[8], alo[8];
  {
    const float* wr = Whh  + (size_t)(g * RPW + arow) * H;
    const float* mr = Whhm + (size_t)(g * RPW + arow) * H;
    #pragma unroll
    for (int c = 0; c < 8; ++c) {
      const int jb = w * 256 + c * 32 + klane * 8;
      f32x4 w0 = *(const f32x4*)(wr + jb),     m0 = *(const f32x4*)(mr + jb);
      f32x4 w1 = *(const f32x4*)(wr + jb + 4), m1 = *(const f32x4*)(mr + jb + 4);
      float wf[8] = { w0.x*m0.x, w0.y*m0.y, w0.z*m0.z, w0.w*m0.w,
                      w1.x*m1.x, w1.y*m1.y, w1.z*m1.z, w1.w*m1.w };
      #pragma unroll
      for (int i = 0; i < 8; ++i) {
        unsigned int uh = __float_as_uint(wf[i]) & 0xffff0000u;
        float fl = wf[i] - __uint_as_float(uh);
        ahi[c][i] = (short)(uh >> 16);
        alo[c][i] = (short)(__float_as_uint(fl) >> 16);
      }
    }
  }

  // ---- per-lane persistent state ----
  const int sidx = bo * H + row;
  float h  = h0[sidx], rr_ = r0[sidx], u = u0[sidx];
  float p  = prel[row], psyn = 1.0f / p;
  float wih = Wih[row], oih = offih[row];
  float wz = Whz[(row >> 7) * H + row] * Whzm[(row >> 7) * H + row];
  float ht = 1.0f / (1.0f + __expf(-8.0f * (h - 0.5f)));

  const float INV_TAU = 1.0f / 0.01f, INV_TD = 1.0f / 0.2f, INV_TF = 1.0f / 1.5f;
  const int sidx3 = ((row >> 3) << 7) + (bo << 3) + (row & 7);  // [j>>3][b][j&7]

  unsigned int* myflag = flags + (g << 2) + w;
  const unsigned int* pollp = flags + (lane << 2);

#define WAITV(n) { asm volatile("s_waitcnt vmcnt(" #n ")" ::: "memory"); \
                   __builtin_amdgcn_sched_barrier(0); }

  // ---- publish s_0 packed, ack, per-wave flag ----
  {
    unsigned int pk = pack_split(ht * rr_ * u * psyn);
    unsigned int* ap = sbuf + sidx3;
    asm volatile("global_store_dword %0, %1, off sc0 sc1" :: "v"(ap), "v"(pk) : "memory");
    WAITV(0);
    if (lane == 0) {
      unsigned int one = 1u;
      asm volatile("global_store_dword %0, %1, off sc0 sc1" :: "v"(myflag), "v"(one) : "memory");
    }
  }

  float* ph = dout + H_OFF + (size_t)bo * (SEQ * H) + row;
  float* pr = dout + R_OFF + (size_t)bo * (SEQ * H) + row;
  float* pu = dout + U_OFF + (size_t)bo * (SEQ * H) + row;
  float* pz = zpart + (size_t)g * BATCH + (w << 2) + lane;  // valid when lane < 4
  const float* ip = Irep + bo;
  float Itc = ip[0];

#define CHUNK(c, n) { WAITV(n); \
    u32x4 q0 = ld[2*(c)], q1 = ld[2*(c)+1]; \
    s16x8 bh, bl; \
    bh[0]=(short)(q0.x>>16); bl[0]=(short)q0.x; \
    bh[1]=(short)(q0.y>>16); bl[1]=(short)q0.y; \
    bh[2]=(short)(q0.z>>16); bl[2]=(short)q0.z; \
    bh[3]=(short)(q0.w>>16); bl[3]=(short)q0.w; \
    bh[4]=(short)(q1.x>>16); bl[4]=(short)q1.x; \
    bh[5]=(short)(q1.y>>16); bl[5]=(short)q1.y; \
    bh[6]=(short)(q1.z>>16); bl[6]=(short)q1.z; \
    bh[7]=(short)(q1.w>>16); bl[7]=(short)q1.w; \
    acc = __builtin_amdgcn_mfma_f32_16x16x32_bf16(ahi[c], bh, acc, 0, 0, 0); \
    acc = __builtin_amdgcn_mfma_f32_16x16x32_bf16(ahi[c], bl, acc, 0, 0, 0); \
    acc = __builtin_amdgcn_mfma_f32_16x16x32_bf16(alo[c], bh, acc, 0, 0, 0); \
    acc = __builtin_amdgcn_mfma_f32_16x16x32_bf16(alo[c], bl, acc, 0, 0, 0); }

  for (int t = 0; t < SEQ; ++t) {
    // ---- wait until all 256 waves have published s_t ----
    const unsigned int tgt = (unsigned int)(t + 1);
    for (int it = 0; it < (1 << 16); ++it) {
      u32x4 f;
      asm volatile("global_load_dwordx4 %0, %1, off sc0 sc1" : "=v"(f) : "v"(pollp) : "memory");
      asm volatile("s_waitcnt vmcnt(0)" ::: "memory");
      if (__all((int)((f.x >= tgt) & (f.y >= tgt) & (f.z >= tgt) & (f.w >= tgt)))) break;
    }
    __builtin_amdgcn_sched_barrier(0);

    // ---- issue this wave's 16 B-fragment loads (K-slice, all 16 batches) ----
    const unsigned int* sb = sbuf + (t & 1) * (BATCH * H);
    u32x4 ld[16];
    #pragma unroll
    for (int c = 0; c < 8; ++c) {
      const unsigned int* ap = sb + ((w * 32 + c * 4 + klane) * 128 + arow * 8);
      asm volatile("global_load_dwordx4 %0, %1, off sc0 sc1" : "=v"(ld[2*c])   : "v"(ap)     : "memory");
      asm volatile("global_load_dwordx4 %0, %1, off sc0 sc1" : "=v"(ld[2*c+1]) : "v"(ap + 4) : "memory");
    }

    // ---- 16x16xK GEMM slice via split-bf16 MFMA ----
    f32x4 acc = {0.f, 0.f, 0.f, 0.f};
    CHUNK(0,14) CHUNK(1,12) CHUNK(2,10) CHUNK(3,8)
    CHUNK(4,6)  CHUNK(5,4)  CHUNK(6,2)  CHUNK(7,0)

    // ---- cross-wave K reduce (C: row=(lane>>4)*4+i, col=lane&15) ----
    const int pbuf = t & 1;
    redC[pbuf][w][klane * 4 + 0][arow] = acc.x;
    redC[pbuf][w][klane * 4 + 1][arow] = acc.y;
    redC[pbuf][w][klane * 4 + 2][arow] = acc.z;
    redC[pbuf][w][klane * 4 + 3][arow] = acc.w;
    __syncthreads();
    float rec = redC[pbuf][0][ro][bo] + redC[pbuf][1][ro][bo]
              + redC[pbuf][2][ro][bo] + redC[pbuf][3][ro][bo];

    // ---- state update (n == 0 identically) ----
    float ext = Itc * wih + oih;
    float hn  = h + ((-h + rec + ext) * INV_TAU) * 0.001f;
    float htn = 1.0f / (1.0f + __expf(-8.0f * (hn - 0.5f)));
    float rn  = rr_ + ((1.0f - rr_) * INV_TD - 50.0f * u * rr_ * ht) * 0.001f;
    float un  = u + ((p - u) * INV_TF + 50.0f * p * (1.0f - u) * ht) * 0.001f;

    // ---- publish s_{t+1}: packed store, ack, per-wave flag ----
    {
      unsigned int pk = pack_split(htn * rn * un * psyn);
      unsigned int* ap = sbuf + ((t + 1) & 1) * (BATCH * H) + sidx3;
      asm volatile("global_store_dword %0, %1, off sc0 sc1" :: "v"(ap), "v"(pk) : "memory");
      WAITV(0);
      if (lane == 0) {
        unsigned int fv = (unsigned int)(t + 2);
        asm volatile("global_store_dword %0, %1, off sc0 sc1" :: "v"(myflag), "v"(fv) : "memory");
      }
    }

    // ---- outputs (overlap other WGs' detect) ----
    ph[(size_t)t * H] = hn; pr[(size_t)t * H] = rn; pu[(size_t)t * H] = un;
    float zl = htn * wz;
    zl += __shfl_xor(zl, 4); zl += __shfl_xor(zl, 8);
    zl += __shfl_xor(zl, 16); zl += __shfl_xor(zl, 32);
    if (lane < 4) pz[(size_t)t * (G * BATCH)] = zl;

    Itc = ip[(size_t)(t + 1) * BATCH];   // prefetch next I (pad covers t+1==SEQ)
    h = hn; ht = htn; rr_ = rn; u = un;
  }
#undef CHUNK
#undef WAITV
}

__global__ void zred_kernel(const float* __restrict__ zpart, const float* __restrict__ offhz,
                            float* __restrict__ zout) {
  int tid = blockIdx.x * blockDim.x + threadIdx.x;
  if (tid >= BATCH * SEQ * NOUT) return;
  int b = tid / (SEQ * NOUT);
  int rem = tid - b * (SEQ * NOUT);
  int t = rem >> 3, o = rem & 7;
  float acc = offhz[o];
  #pragma unroll
  for (int k = 0; k < G / NOUT; ++k)
    acc += zpart[((size_t)t * G + o * (G / NOUT) + k) * BATCH + b];
  zout[tid] = acc;
}

extern "C" void kernel_launch(void* const* d_in, const int* in_sizes, int n_in,
                              void* d_out, int out_size, void* d_ws, size_t ws_size,
                              hipStream_t stream) {
  const float* I     = (const float*)d_in[0];
  const float* h0    = (const float*)d_in[1];
  const float* r0    = (const float*)d_in[2];
  const float* u0    = (const float*)d_in[3];
  const float* Wih   = (const float*)d_in[4];
  const float* offih = (const float*)d_in[5];
  const float* Whh   = (const float*)d_in[6];
  const float* Whz   = (const float*)d_in[7];
  const float* offhz = (const float*)d_in[8];
  const float* prel  = (const float*)d_in[9];
  const float* Whhm  = (const float*)d_in[10];
  const float* Whzm  = (const float*)d_in[11];
  float* out = (float*)d_out;

  unsigned int* flags = (unsigned int*)((char*)d_ws + FLAGS_OFF);
  unsigned int* sbuf  = (unsigned int*)((char*)d_ws + SBUF_OFF);
  float* Irep  = (float*)((char*)d_ws + IREP_OFF);
  float* zpart = (float*)((char*)d_ws + ZPART_OFF);

  hipMemsetAsync(d_out, 0, (size_t)H_OFF * sizeof(float), stream);  // n_all == 0
  init_kernel<<<128, 256, 0, stream>>>(I, Irep, flags);
  rnn_persist<<<G, TPB, 0, stream>>>(h0, r0, u0, Wih, offih, Whh, Whz, prel, Whhm, Whzm,
                                     Irep, sbuf, flags, zpart, out);
  zred_kernel<<<(BATCH * SEQ * NOUT + 255) / 256, 256, 0, stream>>>(zpart, offhz, out + Z_OFF);
}

// Round 7
// 5189.142 us; speedup vs baseline: 3.3339x; 1.3408x over previous
//
#include <hip/hip_runtime.h>
#include <cstdint>
#include <cstddef>

typedef float f32x4 __attribute__((ext_vector_type(4)));
typedef unsigned int u32x4 __attribute__((ext_vector_type(4)));
typedef short s16x8 __attribute__((ext_vector_type(8)));

#define H     1024
#define BATCH 16
#define SEQ   2000
#define NOUT  8
#define G     64       // persistent workgroups, 16 rows each
#define RPW   16
#define TPB   256

// d_out offsets (floats): n_all, h_all, r_all, u_all, z_all
#define H_OFF 32768000
#define R_OFF 65536000
#define U_OFF 98304000
#define Z_OFF 131072000

// ws layout (bytes)
#define SBUF_OFF  8192       // double-buffered packed s: 2*16384 u32, layout [j>>3][b][j&7]
#define IREP_OFF  139264     // I repacked [t][b] (+pad)
#define ZPART_OFF 267392     // zpart [t][g][b]

#define TAG(tau) ((unsigned int)(((tau) >> 1) & 1))

__global__ void init_kernel(const float* __restrict__ I, float* __restrict__ Irep,
                            unsigned int* __restrict__ sbuf) {
  int tid = blockIdx.x * blockDim.x + threadIdx.x;
  if (tid < SEQ * BATCH) {
    int t = tid >> 4, b = tid & 15;
    Irep[tid] = I[b * SEQ + t];            // I is [B, SEQ, 1]
  }
  if (tid < 2 * BATCH * H) {               // pre-tag both buffers stale (tag=1; s_0/s_1 expect 0)
    unsigned int* ap = sbuf + tid; unsigned int v = 1u;
    asm volatile("global_store_dword %0, %1, off sc0 sc1" :: "v"(ap), "v"(v) : "memory");
  }
}

// split f into truncated-bf16 hi + truncated-bf16 lo, packed (hi<<16)|lo
__device__ __forceinline__ unsigned int pack_split(float f) {
  unsigned int uh = __float_as_uint(f) & 0xffff0000u;
  float fl = f - __uint_as_float(uh);
  return uh | (__float_as_uint(fl) >> 16);
}

__global__ __launch_bounds__(TPB, 1) void rnn_persist(
    const float* __restrict__ h0, const float* __restrict__ r0, const float* __restrict__ u0,
    const float* __restrict__ Wih, const float* __restrict__ offih,
    const float* __restrict__ Whh, const float* __restrict__ Whz,
    const float* __restrict__ prel, const float* __restrict__ Whhm, const float* __restrict__ Whzm,
    const float* __restrict__ Irep, unsigned int* __restrict__ sbuf,
    float* __restrict__ zpart, float* __restrict__ dout)
{
  __shared__ float redC[2][4][16][17];   // [parity][wave][row][batch(+pad)]

  const int g = blockIdx.x, tid = threadIdx.x;
  const int lane = tid & 63, w = tid >> 6;
  const int arow  = lane & 15;           // MFMA A row / C col
  const int klane = lane >> 4;           // 0..3: k-subgroup
  const int ro = lane >> 2, bo = (w << 2) + (lane & 3);   // owned state (row, batch)
  const int row = g * RPW + ro;

  // ---- one-time: masked W_hh -> split-bf16 fragments in VGPRs (64 regs) ----
  s16x8 ahi[8], alo[8];
  {
    const float* wr = Whh  + (size_t)(g * RPW + arow) * H;
    const float* mr = Whhm + (size_t)(g * RPW + arow) * H;
    #pragma unroll
    for (int c = 0; c < 8; ++c) {
      const int jb = w * 256 + c * 32 + klane * 8;
      f32x4 w0 = *(const f32x4*)(wr + jb),     m0 = *(const f32x4*)(mr + jb);
      f32x4 w1 = *(const f32x4*)(wr + jb + 4), m1 = *(const f32x4*)(mr + jb + 4);
      float wf[8] = { w0.x*m0.x, w0.y*m0.y, w0.z*m0.z, w0.w*m0.w,
                      w1.x*m1.x, w1.y*m1.y, w1.z*m1.z, w1.w*m1.w };
      #pragma unroll
      for (int i = 0; i < 8; ++i) {
        unsigned int uh = __float_as_uint(wf[i]) & 0xffff0000u;
        float fl = wf[i] - __uint_as_float(uh);
        ahi[c][i] = (short)(uh >> 16);
        alo[c][i] = (short)(__float_as_uint(fl) >> 16);
      }
    }
  }

  // ---- per-lane persistent state ----
  const int sidx = bo * H + row;
  float h  = h0[sidx], rr_ = r0[sidx], u = u0[sidx];
  float p  = prel[row], psyn = 1.0f / p;
  float wih = Wih[row], oih = offih[row];
  float wz = Whz[(row >> 7) * H + row] * Whzm[(row >> 7) * H + row];
  float ht = 1.0f / (1.0f + __expf(-8.0f * (h - 0.5f)));

  const float INV_TAU = 1.0f / 0.01f, INV_TD = 1.0f / 0.2f, INV_TF = 1.0f / 1.5f;
  const int sidx3 = ((row >> 3) << 7) + (bo << 3) + (row & 7);  // [j>>3][b][j&7]

#define WAITV(n) { asm volatile("s_waitcnt vmcnt(" #n ")" ::: "memory"); \
                   __builtin_amdgcn_sched_barrier(0); }

  // ---- publish s_0 (tagged, fire-and-forget) ----
  {
    unsigned int pk = (pack_split(ht * rr_ * u * psyn) & ~1u) | TAG(0);
    unsigned int* ap = sbuf + sidx3;
    asm volatile("global_store_dword %0, %1, off sc0 sc1" :: "v"(ap), "v"(pk) : "memory");
  }

  float* ph = dout + H_OFF + (size_t)bo * (SEQ * H) + row;
  float* pr = dout + R_OFF + (size_t)bo * (SEQ * H) + row;
  float* pu = dout + U_OFF + (size_t)bo * (SEQ * H) + row;
  float* pz = zpart + (size_t)g * BATCH + (w << 2) + lane;  // valid when lane < 4
  const float* ip = Irep + bo;
  float Itc = ip[0];

  // cheap-poll sample: one element from each source WG / producer wave pair
  // lane samples WG sg = 16w + (lane&15), producer wave wp = lane>>4:
  // element (j = 16*sg + wp, b = 4*wp)  -> u32 index 256*sg + 33*wp
  const int samp_off = ((16 * w + (lane & 15)) << 8) + 33 * (lane >> 4);

#define ISSUE_ALL { _Pragma("unroll") for (int c = 0; c < 8; ++c) { \
    const unsigned int* ap = sb + ((w * 32 + c * 4 + klane) * 128 + arow * 8); \
    asm volatile("global_load_dwordx4 %0, %1, off sc0 sc1" : "=v"(ld[2*c])   : "v"(ap)     : "memory"); \
    asm volatile("global_load_dwordx4 %0, %1, off sc0 sc1" : "=v"(ld[2*c+1]) : "v"(ap + 4) : "memory"); } }

#define VERIFY(okv) { unsigned int bad = 0; \
    _Pragma("unroll") for (int k2 = 0; k2 < 16; ++k2) { \
      u32x4 v = ld[k2]; bad |= (v.x ^ tg) | (v.y ^ tg) | (v.z ^ tg) | (v.w ^ tg); } \
    okv = __all((int)((bad & 1u) == 0)); }

#define CHUNK(c) { \
    u32x4 q0 = ld[2*(c)], q1 = ld[2*(c)+1]; \
    s16x8 bh, bl; \
    bh[0]=(short)(q0.x>>16); bl[0]=(short)q0.x; \
    bh[1]=(short)(q0.y>>16); bl[1]=(short)q0.y; \
    bh[2]=(short)(q0.z>>16); bl[2]=(short)q0.z; \
    bh[3]=(short)(q0.w>>16); bl[3]=(short)q0.w; \
    bh[4]=(short)(q1.x>>16); bl[4]=(short)q1.x; \
    bh[5]=(short)(q1.y>>16); bl[5]=(short)q1.y; \
    bh[6]=(short)(q1.z>>16); bl[6]=(short)q1.z; \
    bh[7]=(short)(q1.w>>16); bl[7]=(short)q1.w; \
    acc = __builtin_amdgcn_mfma_f32_16x16x32_bf16(ahi[c], bh, acc, 0, 0, 0); \
    acc = __builtin_amdgcn_mfma_f32_16x16x32_bf16(ahi[c], bl, acc, 0, 0, 0); \
    acc = __builtin_amdgcn_mfma_f32_16x16x32_bf16(alo[c], bh, acc, 0, 0, 0); \
    acc = __builtin_amdgcn_mfma_f32_16x16x32_bf16(alo[c], bl, acc, 0, 0, 0); }

  for (int t = 0; t < SEQ; ++t) {
    const unsigned int tg = TAG(t);
    const unsigned int* sb = sbuf + (t & 1) * (BATCH * H);

    // ---- cheap poll: wait until all sampled elements carry this step's tag ----
    {
      const unsigned int* sp = sb + samp_off;
      for (int it = 0; it < (1 << 16); ++it) {
        unsigned int sv;
        asm volatile("global_load_dword %0, %1, off sc0 sc1" : "=v"(sv) : "v"(sp) : "memory");
        asm volatile("s_waitcnt vmcnt(0)" ::: "memory");
        if (__all((int)(((sv ^ tg) & 1u) == 0))) break;
      }
      __builtin_amdgcn_sched_barrier(0);
    }

    // ---- bulk load K-slice (16 dwordx4), verify all tags, rare retry ----
    u32x4 ld[16];
    ISSUE_ALL;
    WAITV(0);
    {
      int ok; VERIFY(ok);
      int guard = 0;
      while (!ok && ++guard < (1 << 12)) { ISSUE_ALL; WAITV(0); VERIFY(ok); }
    }

    // ---- 16x16xK GEMM slice via split-bf16 MFMA ----
    f32x4 acc = {0.f, 0.f, 0.f, 0.f};
    CHUNK(0) CHUNK(1) CHUNK(2) CHUNK(3)
    CHUNK(4) CHUNK(5) CHUNK(6) CHUNK(7)

    // ---- cross-wave K reduce (C: row=klane*4+i, col=arow) ----
    const int pbuf = t & 1;
    redC[pbuf][w][klane * 4 + 0][arow] = acc.x;
    redC[pbuf][w][klane * 4 + 1][arow] = acc.y;
    redC[pbuf][w][klane * 4 + 2][arow] = acc.z;
    redC[pbuf][w][klane * 4 + 3][arow] = acc.w;
    __syncthreads();
    float rec = redC[pbuf][0][ro][bo] + redC[pbuf][1][ro][bo]
              + redC[pbuf][2][ro][bo] + redC[pbuf][3][ro][bo];

    // ---- state update (n == 0 identically) ----
    float ext = Itc * wih + oih;
    float hn  = h + ((-h + rec + ext) * INV_TAU) * 0.001f;
    float htn = 1.0f / (1.0f + __expf(-8.0f * (hn - 0.5f)));
    float rn  = rr_ + ((1.0f - rr_) * INV_TD - 50.0f * u * rr_ * ht) * 0.001f;
    float un  = u + ((p - u) * INV_TF + 50.0f * p * (1.0f - u) * ht) * 0.001f;

    // ---- publish s_{t+1}: tagged single store, no ack, no flags ----
    {
      unsigned int pk = (pack_split(htn * rn * un * psyn) & ~1u) | TAG(t + 1);
      unsigned int* ap = sbuf + ((t + 1) & 1) * (BATCH * H) + sidx3;
      asm volatile("global_store_dword %0, %1, off sc0 sc1" :: "v"(ap), "v"(pk) : "memory");
    }

    // ---- outputs (off critical path) ----
    ph[(size_t)t * H] = hn; pr[(size_t)t * H] = rn; pu[(size_t)t * H] = un;
    float zl = htn * wz;
    zl += __shfl_xor(zl, 4); zl += __shfl_xor(zl, 8);
    zl += __shfl_xor(zl, 16); zl += __shfl_xor(zl, 32);
    if (lane < 4) pz[(size_t)t * (G * BATCH)] = zl;

    Itc = ip[(size_t)(t + 1) * BATCH];   // prefetch next I (pad covers t+1==SEQ)
    h = hn; ht = htn; rr_ = rn; u = un;
  }
#undef CHUNK
#undef VERIFY
#undef ISSUE_ALL
#undef WAITV
}

__global__ void zred_kernel(const float* __restrict__ zpart, const float* __restrict__ offhz,
                            float* __restrict__ zout) {
  int tid = blockIdx.x * blockDim.x + threadIdx.x;
  if (tid >= BATCH * SEQ * NOUT) return;
  int b = tid / (SEQ * NOUT);
  int rem = tid - b * (SEQ * NOUT);
  int t = rem >> 3, o = rem & 7;
  float acc = offhz[o];
  #pragma unroll
  for (int k = 0; k < G / NOUT; ++k)
    acc += zpart[((size_t)t * G + o * (G / NOUT) + k) * BATCH + b];
  zout[tid] = acc;
}

extern "C" void kernel_launch(void* const* d_in, const int* in_sizes, int n_in,
                              void* d_out, int out_size, void* d_ws, size_t ws_size,
                              hipStream_t stream) {
  const float* I     = (const float*)d_in[0];
  const float* h0    = (const float*)d_in[1];
  const float* r0    = (const float*)d_in[2];
  const float* u0    = (const float*)d_in[3];
  const float* Wih   = (const float*)d_in[4];
  const float* offih = (const float*)d_in[5];
  const float* Whh   = (const float*)d_in[6];
  const float* Whz   = (const float*)d_in[7];
  const float* offhz = (const float*)d_in[8];
  const float* prel  = (const float*)d_in[9];
  const float* Whhm  = (const float*)d_in[10];
  const float* Whzm  = (const float*)d_in[11];
  float* out = (float*)d_out;

  unsigned int* sbuf  = (unsigned int*)((char*)d_ws + SBUF_OFF);
  float* Irep  = (float*)((char*)d_ws + IREP_OFF);
  float* zpart = (float*)((char*)d_ws + ZPART_OFF);

  hipMemsetAsync(d_out, 0, (size_t)H_OFF * sizeof(float), stream);  // n_all == 0
  init_kernel<<<128, 256, 0, stream>>>(I, Irep, sbuf);
  rnn_persist<<<G, TPB, 0, stream>>>(h0, r0, u0, Wih, offih, Whh, Whz, prel, Whhm, Whzm,
                                     Irep, sbuf, zpart, out);
  zred_kernel<<<(BATCH * SEQ * NOUT + 255) / 256, 256, 0, stream>>>(zpart, offhz, out + Z_OFF);
}

// Round 8
// 4615.893 us; speedup vs baseline: 3.7479x; 1.1242x over previous
//
#include <hip/hip_runtime.h>
#include <cstdint>
#include <cstddef>

typedef float f32x4 __attribute__((ext_vector_type(4)));
typedef unsigned int u32x4 __attribute__((ext_vector_type(4)));
typedef short s16x8 __attribute__((ext_vector_type(8)));

#define H     1024
#define BATCH 16
#define SEQ   2000
#define NOUT  8
#define G     64       // persistent workgroups, 16 rows each
#define RPW   16
#define TPB   256

// d_out offsets (floats): n_all, h_all, r_all, u_all, z_all
#define H_OFF 32768000
#define R_OFF 65536000
#define U_OFF 98304000
#define Z_OFF 131072000

// ws layout (bytes)
#define SBUF_OFF  8192       // double-buffered packed s: 2*16384 u32, layout [j>>3][b][j&7]
#define IREP_OFF  139264     // I repacked [t][b] (+pad)
#define ZPART_OFF 267392     // zpart [t][g][b]

#define TAG(tau) ((unsigned int)(((tau) >> 1) & 1))

__global__ void init_kernel(const float* __restrict__ I, float* __restrict__ Irep,
                            unsigned int* __restrict__ sbuf) {
  int tid = blockIdx.x * blockDim.x + threadIdx.x;
  if (tid < SEQ * BATCH) {
    int t = tid >> 4, b = tid & 15;
    Irep[tid] = I[b * SEQ + t];            // I is [B, SEQ, 1]
  }
  if (tid < 2 * BATCH * H) {               // pre-tag both buffers stale (tag=1; s_0/s_1 expect 0)
    unsigned int* ap = sbuf + tid; unsigned int v = 1u;
    asm volatile("global_store_dword %0, %1, off sc0 sc1" :: "v"(ap), "v"(v) : "memory");
  }
}

// split f into truncated-bf16 hi + truncated-bf16 lo, packed (hi<<16)|lo
__device__ __forceinline__ unsigned int pack_split(float f) {
  unsigned int uh = __float_as_uint(f) & 0xffff0000u;
  float fl = f - __uint_as_float(uh);
  return uh | (__float_as_uint(fl) >> 16);
}

__global__ __launch_bounds__(TPB, 1) void rnn_persist(
    const float* __restrict__ h0, const float* __restrict__ r0, const float* __restrict__ u0,
    const float* __restrict__ Wih, const float* __restrict__ offih,
    const float* __restrict__ Whh, const float* __restrict__ Whz,
    const float* __restrict__ prel, const float* __restrict__ Whhm, const float* __restrict__ Whzm,
    const float* __restrict__ Irep, unsigned int* __restrict__ sbuf,
    float* __restrict__ zpart, float* __restrict__ dout)
{
  __shared__ float redC[2][4][16][17];   // [parity][wave][row][batch(+pad)]

  const int g = blockIdx.x, tid = threadIdx.x;
  const int lane = tid & 63, w = tid >> 6;
  const int arow  = lane & 15;           // MFMA A row / B col (batch)
  const int klane = lane >> 4;           // 0..3: k-subgroup
  const int ro = lane >> 2, bo = (w << 2) + (lane & 3);   // owned state (row, batch)
  const int row = g * RPW + ro;

  // ---- one-time: masked W_hh -> split-bf16 fragments in VGPRs (64 regs) ----
  s16x8 ahi[8], alo[8];
  {
    const float* wr = Whh  + (size_t)(g * RPW + arow) * H;
    const float* mr = Whhm + (size_t)(g * RPW + arow) * H;
    #pragma unroll
    for (int c = 0; c < 8; ++c) {
      const int jb = w * 256 + c * 32 + klane * 8;
      f32x4 w0 = *(const f32x4*)(wr + jb),     m0 = *(const f32x4*)(mr + jb);
      f32x4 w1 = *(const f32x4*)(wr + jb + 4), m1 = *(const f32x4*)(mr + jb + 4);
      float wf[8] = { w0.x*m0.x, w0.y*m0.y, w0.z*m0.z, w0.w*m0.w,
                      w1.x*m1.x, w1.y*m1.y, w1.z*m1.z, w1.w*m1.w };
      #pragma unroll
      for (int i = 0; i < 8; ++i) {
        unsigned int uh = __float_as_uint(wf[i]) & 0xffff0000u;
        float fl = wf[i] - __uint_as_float(uh);
        ahi[c][i] = (short)(uh >> 16);
        alo[c][i] = (short)(__float_as_uint(fl) >> 16);
      }
    }
  }

  // ---- per-lane persistent state ----
  const int sidx = bo * H + row;
  float h  = h0[sidx], rr_ = r0[sidx], u = u0[sidx];
  float p  = prel[row], psyn = 1.0f / p;
  float wih = Wih[row], oih = offih[row];
  float wz = Whz[(row >> 7) * H + row] * Whzm[(row >> 7) * H + row];
  float ht = 1.0f / (1.0f + __expf(-8.0f * (h - 0.5f)));

  const float INV_TAU = 1.0f / 0.01f, INV_TD = 1.0f / 0.2f, INV_TF = 1.0f / 1.5f;
  const int sidx3 = ((row >> 3) << 7) + (bo << 3) + (row & 7);  // [j>>3][b][j&7]

#define WAITV(n) { asm volatile("s_waitcnt vmcnt(" #n ")" ::: "memory"); \
                   __builtin_amdgcn_sched_barrier(0); }

  // ---- publish s_0 (tagged, fire-and-forget) ----
  {
    unsigned int pk = (pack_split(ht * rr_ * u * psyn) & ~1u) | TAG(0);
    unsigned int* ap = sbuf + sidx3;
    asm volatile("global_store_dword %0, %1, off sc0 sc1" :: "v"(ap), "v"(pk) : "memory");
  }

  float* ph = dout + H_OFF + (size_t)bo * (SEQ * H) + row;
  float* pr = dout + R_OFF + (size_t)bo * (SEQ * H) + row;
  float* pu = dout + U_OFF + (size_t)bo * (SEQ * H) + row;
  float* pz = zpart + (size_t)g * BATCH + (w << 2) + lane;  // valid when lane < 4
  const float* ip = Irep + bo;
  float Itc = ip[0];

// chunk c covers k = c*32 + klane*8 + [0,8); depends on source WGs 16w+2c, 16w+2c+1
#define ISSUE_CHUNK(c) { \
    const unsigned int* ap = sb + ((w * 32 + (c) * 4 + klane) * 128 + arow * 8); \
    asm volatile("global_load_dwordx4 %0, %1, off sc0 sc1" : "=v"(ld[2*(c)])   : "v"(ap)     : "memory"); \
    asm volatile("global_load_dwordx4 %0, %1, off sc0 sc1" : "=v"(ld[2*(c)+1]) : "v"(ap + 4) : "memory"); }

#define VCHK(c, okv) { u32x4 v0 = ld[2*(c)], v1 = ld[2*(c)+1]; \
    unsigned int bad = (v0.x ^ tg) | (v0.y ^ tg) | (v0.z ^ tg) | (v0.w ^ tg) \
                     | (v1.x ^ tg) | (v1.y ^ tg) | (v1.z ^ tg) | (v1.w ^ tg); \
    okv = __all((int)((bad & 1u) == 0)); }

#define DO_CHUNK(c) { \
    u32x4 q0 = ld[2*(c)], q1 = ld[2*(c)+1]; \
    s16x8 bh, bl; \
    bh[0]=(short)(q0.x>>16); bl[0]=(short)q0.x; \
    bh[1]=(short)(q0.y>>16); bl[1]=(short)q0.y; \
    bh[2]=(short)(q0.z>>16); bl[2]=(short)q0.z; \
    bh[3]=(short)(q0.w>>16); bl[3]=(short)q0.w; \
    bh[4]=(short)(q1.x>>16); bl[4]=(short)q1.x; \
    bh[5]=(short)(q1.y>>16); bl[5]=(short)q1.y; \
    bh[6]=(short)(q1.z>>16); bl[6]=(short)q1.z; \
    bh[7]=(short)(q1.w>>16); bl[7]=(short)q1.w; \
    acc = __builtin_amdgcn_mfma_f32_16x16x32_bf16(ahi[c], bh, acc, 0, 0, 0); \
    acc = __builtin_amdgcn_mfma_f32_16x16x32_bf16(ahi[c], bl, acc, 0, 0, 0); \
    acc = __builtin_amdgcn_mfma_f32_16x16x32_bf16(alo[c], bh, acc, 0, 0, 0); \
    acc = __builtin_amdgcn_mfma_f32_16x16x32_bf16(alo[c], bl, acc, 0, 0, 0); }

#define FIRST_PASS(c, n) { WAITV(n); int ok; VCHK(c, ok); \
    if (ok) { DO_CHUNK(c); done |= (1 << (c)); } }

  for (int t = 0; t < SEQ; ++t) {
    const unsigned int tg = TAG(t);
    const unsigned int* sb = sbuf + (t & 1) * (BATCH * H);

    // ---- speculative slice load; per-chunk verify -> MFMA; retry stale chunks ----
    u32x4 ld[16];
    f32x4 acc = {0.f, 0.f, 0.f, 0.f};
    int done = 0;

    ISSUE_CHUNK(0) ISSUE_CHUNK(1) ISSUE_CHUNK(2) ISSUE_CHUNK(3)
    ISSUE_CHUNK(4) ISSUE_CHUNK(5) ISSUE_CHUNK(6) ISSUE_CHUNK(7)

    FIRST_PASS(0,14) FIRST_PASS(1,12) FIRST_PASS(2,10) FIRST_PASS(3,8)
    FIRST_PASS(4,6)  FIRST_PASS(5,4)  FIRST_PASS(6,2)  FIRST_PASS(7,0)

    {
      int guard = 0;
      while (done != 0xff && ++guard < (1 << 13)) {
        #pragma unroll
        for (int c = 0; c < 8; ++c)
          if (!(done & (1 << c))) ISSUE_CHUNK(c);
        WAITV(0);
        #pragma unroll
        for (int c = 0; c < 8; ++c)
          if (!(done & (1 << c))) {
            int ok; VCHK(c, ok);
            if (ok) { DO_CHUNK(c); done |= (1 << c); }
          }
      }
    }

    // ---- cross-wave K reduce (C: row=klane*4+i, col=arow) ----
    const int pbuf = t & 1;
    redC[pbuf][w][klane * 4 + 0][arow] = acc.x;
    redC[pbuf][w][klane * 4 + 1][arow] = acc.y;
    redC[pbuf][w][klane * 4 + 2][arow] = acc.z;
    redC[pbuf][w][klane * 4 + 3][arow] = acc.w;
    __syncthreads();
    float rec = redC[pbuf][0][ro][bo] + redC[pbuf][1][ro][bo]
              + redC[pbuf][2][ro][bo] + redC[pbuf][3][ro][bo];

    // ---- state update (n == 0 identically) ----
    float ext = Itc * wih + oih;
    float hn  = h + ((-h + rec + ext) * INV_TAU) * 0.001f;
    float htn = 1.0f / (1.0f + __expf(-8.0f * (hn - 0.5f)));
    float rn  = rr_ + ((1.0f - rr_) * INV_TD - 50.0f * u * rr_ * ht) * 0.001f;
    float un  = u + ((p - u) * INV_TF + 50.0f * p * (1.0f - u) * ht) * 0.001f;

    // ---- publish s_{t+1}: tagged single store, no ack, no flags ----
    {
      unsigned int pk = (pack_split(htn * rn * un * psyn) & ~1u) | TAG(t + 1);
      unsigned int* ap = sbuf + ((t + 1) & 1) * (BATCH * H) + sidx3;
      asm volatile("global_store_dword %0, %1, off sc0 sc1" :: "v"(ap), "v"(pk) : "memory");
    }

    // ---- outputs (off critical path) ----
    ph[(size_t)t * H] = hn; pr[(size_t)t * H] = rn; pu[(size_t)t * H] = un;
    float zl = htn * wz;
    zl += __shfl_xor(zl, 4); zl += __shfl_xor(zl, 8);
    zl += __shfl_xor(zl, 16); zl += __shfl_xor(zl, 32);
    if (lane < 4) pz[(size_t)t * (G * BATCH)] = zl;

    Itc = ip[(size_t)(t + 1) * BATCH];   // prefetch next I (pad covers t+1==SEQ)
    h = hn; ht = htn; rr_ = rn; u = un;
  }
#undef FIRST_PASS
#undef DO_CHUNK
#undef VCHK
#undef ISSUE_CHUNK
#undef WAITV
}

__global__ void zred_kernel(const float* __restrict__ zpart, const float* __restrict__ offhz,
                            float* __restrict__ zout) {
  int tid = blockIdx.x * blockDim.x + threadIdx.x;
  if (tid >= BATCH * SEQ * NOUT) return;
  int b = tid / (SEQ * NOUT);
  int rem = tid - b * (SEQ * NOUT);
  int t = rem >> 3, o = rem & 7;
  float acc = offhz[o];
  #pragma unroll
  for (int k = 0; k < G / NOUT; ++k)
    acc += zpart[((size_t)t * G + o * (G / NOUT) + k) * BATCH + b];
  zout[tid] = acc;
}

extern "C" void kernel_launch(void* const* d_in, const int* in_sizes, int n_in,
                              void* d_out, int out_size, void* d_ws, size_t ws_size,
                              hipStream_t stream) {
  const float* I     = (const float*)d_in[0];
  const float* h0    = (const float*)d_in[1];
  const float* r0    = (const float*)d_in[2];
  const float* u0    = (const float*)d_in[3];
  const float* Wih   = (const float*)d_in[4];
  const float* offih = (const float*)d_in[5];
  const float* Whh   = (const float*)d_in[6];
  const float* Whz   = (const float*)d_in[7];
  const float* offhz = (const float*)d_in[8];
  const float* prel  = (const float*)d_in[9];
  const float* Whhm  = (const float*)d_in[10];
  const float* Whzm  = (const float*)d_in[11];
  float* out = (float*)d_out;

  unsigned int* sbuf  = (unsigned int*)((char*)d_ws + SBUF_OFF);
  float* Irep  = (float*)((char*)d_ws + IREP_OFF);
  float* zpart = (float*)((char*)d_ws + ZPART_OFF);

  hipMemsetAsync(d_out, 0, (size_t)H_OFF * sizeof(float), stream);  // n_all == 0
  init_kernel<<<128, 256, 0, stream>>>(I, Irep, sbuf);
  rnn_persist<<<G, TPB, 0, stream>>>(h0, r0, u0, Wih, offih, Whh, Whz, prel, Whhm, Whzm,
                                     Irep, sbuf, zpart, out);
  zred_kernel<<<(BATCH * SEQ * NOUT + 255) / 256, 256, 0, stream>>>(zpart, offhz, out + Z_OFF);
}